// Round 1
// baseline (1139.992 us; speedup 1.0000x reference)
//
#include <hip/hip_runtime.h>
#include <hip/hip_bf16.h>
#include <math.h>

// Problem constants
#define N_E    4096      // number of codes
#define EDIM   256       // embedding dim (K)
#define NB     2         // batch
#define SPAT   8192      // 8*32*32 spatial per (b,c)
#define NROWS  16384     // NB * SPAT flattened rows
#define ZELEMS 4194304   // 2*256*8*32*32

// Output offsets (flat float32 in return order)
#define OFF_LOSS    0
#define OFF_ZQ      1
#define OFF_PERP    4194305
#define OFF_ONEHOT  4194306
#define OFF_IDX     71303170
#define OFF_ZOUT    71319554
#define OFF_EMA     75513858

// ---------------------------------------------------------------------------
// K0: se[c] = sum_k W[c][k]^2   (one wave per code)
// ---------------------------------------------------------------------------
__global__ __launch_bounds__(256) void se_kernel(const float* __restrict__ W,
                                                 float* __restrict__ se) {
    int wid  = (blockIdx.x * 256 + threadIdx.x) >> 6;   // wave id = code id
    int lane = threadIdx.x & 63;
    if (wid < N_E) {
        const float4 v = *(const float4*)(W + (size_t)wid * EDIM + lane * 4);
        float s = v.x * v.x + v.y * v.y + v.z * v.z + v.w * v.w;
        #pragma unroll
        for (int off = 32; off > 0; off >>= 1) s += __shfl_down(s, off);
        if (lane == 0) se[wid] = s;
    }
}

// ---------------------------------------------------------------------------
// K1: argmin over codes.  Tiled fp32 "GEMM": BM=64 rows, BN=128 codes, BK=32.
// 512 threads, each computes a 4x4 micro-tile.
// d = (sz[row] + se[code]) - 2*dot   (mirrors reference rounding)
// ---------------------------------------------------------------------------
__global__ __launch_bounds__(512) void argmin_kernel(
        const float* __restrict__ z, const float* __restrict__ W,
        const float* __restrict__ se,
        int* __restrict__ idx_ws, int* __restrict__ counts,
        float* __restrict__ out_idx, float* __restrict__ out_onehot) {
    __shared__ float As[32][64];    // [kk][row]  8KB
    __shared__ float Bs[32][128];   // [kk][col] 16KB
    __shared__ float szp[4][64];
    __shared__ float sz_s[64];
    __shared__ float bD[32][64];    // [cg][row]
    __shared__ int   bI[32][64];

    const int tid = threadIdx.x;
    const int r0  = blockIdx.x * 64;        // first row of tile
    const int bb  = r0 >> 13;               // batch index
    const int sp0 = r0 & (SPAT - 1);        // spatial base (multiple of 64)
    const float* zb = z + (size_t)bb * (EDIM * SPAT) + sp0;

    // row norms: 256 threads, 4 k-chunks of 64 each
    if (tid < 256) {
        int lr = tid & 63, kq = tid >> 6;
        float s = 0.f;
        const float* p = zb + lr + (size_t)(kq * 64) * SPAT;
        for (int k = 0; k < 64; ++k) {
            float v = p[(size_t)k * SPAT];
            s += v * v;
        }
        szp[kq][lr] = s;
    }
    __syncthreads();
    if (tid < 64)
        sz_s[tid] = ((szp[0][tid] + szp[1][tid]) + szp[2][tid]) + szp[3][tid];
    // (barrier before first use happens inside the main loop)

    const int rg = tid >> 5;          // 0..15 -> rows rg*4..+3
    const int cg = tid & 31;          // 0..31 -> cols cg*4..+3 within chunk
    // A staging: 2048 words / 512 threads = 1 float4 each
    const int a_kk = tid >> 4;              // 0..31
    const int a_lr = (tid & 15) << 2;       // 0,4,..,60
    // B staging: 4096 words / 512 threads = 2 float4 each
    const int b_lc = tid & 127;             // 0..127
    const int b_kq = tid >> 7;              // 0..3

    float bestD[4];
    int   bestI[4];
    #pragma unroll
    for (int i = 0; i < 4; ++i) { bestD[i] = 3.4e38f; bestI[i] = 0; }

    for (int c0 = 0; c0 < N_E; c0 += 128) {
        float acc[4][4];
        #pragma unroll
        for (int i = 0; i < 4; ++i)
            #pragma unroll
            for (int j = 0; j < 4; ++j) acc[i][j] = 0.f;

        for (int k0 = 0; k0 < EDIM; k0 += 32) {
            __syncthreads();   // previous iter's LDS reads done
            // stage A tile (coalesced rows of 64 floats)
            const float4 av = *(const float4*)(zb + (size_t)(k0 + a_kk) * SPAT + a_lr);
            *(float4*)&As[a_kk][a_lr] = av;
            // stage B tile (transpose k-major into LDS)
            #pragma unroll
            for (int t = 0; t < 2; ++t) {
                int kk = b_kq * 8 + t * 4;
                const float4 bv = *(const float4*)(W + (size_t)(c0 + b_lc) * EDIM + k0 + kk);
                Bs[kk + 0][b_lc] = bv.x;
                Bs[kk + 1][b_lc] = bv.y;
                Bs[kk + 2][b_lc] = bv.z;
                Bs[kk + 3][b_lc] = bv.w;
            }
            __syncthreads();
            #pragma unroll
            for (int kk = 0; kk < 32; ++kk) {
                const float4 a = *(const float4*)&As[kk][rg << 2];
                const float4 b = *(const float4*)&Bs[kk][cg << 2];
                acc[0][0] += a.x * b.x; acc[0][1] += a.x * b.y;
                acc[0][2] += a.x * b.z; acc[0][3] += a.x * b.w;
                acc[1][0] += a.y * b.x; acc[1][1] += a.y * b.y;
                acc[1][2] += a.y * b.z; acc[1][3] += a.y * b.w;
                acc[2][0] += a.z * b.x; acc[2][1] += a.z * b.y;
                acc[2][2] += a.z * b.z; acc[2][3] += a.z * b.w;
                acc[3][0] += a.w * b.x; acc[3][1] += a.w * b.y;
                acc[3][2] += a.w * b.z; acc[3][3] += a.w * b.w;
            }
        }
        // epilogue: distances + running argmin (codes ascend => first-min kept)
        #pragma unroll
        for (int i = 0; i < 4; ++i) {
            const float szr = sz_s[(rg << 2) + i];
            #pragma unroll
            for (int j = 0; j < 4; ++j) {
                const int code = c0 + (cg << 2) + j;
                const float d = (szr + se[code]) - 2.0f * acc[i][j];
                if (d < bestD[i]) { bestD[i] = d; bestI[i] = code; }
            }
        }
    }

    // cross-thread reduction per row (lexicographic on (d, idx))
    #pragma unroll
    for (int i = 0; i < 4; ++i) {
        bD[cg][(rg << 2) + i] = bestD[i];
        bI[cg][(rg << 2) + i] = bestI[i];
    }
    __syncthreads();
    if (tid < 64) {
        float d0 = bD[0][tid];
        int   i0 = bI[0][tid];
        #pragma unroll
        for (int c = 1; c < 32; ++c) {
            float d = bD[c][tid];
            int   ii = bI[c][tid];
            if (d < d0 || (d == d0 && ii < i0)) { d0 = d; i0 = ii; }
        }
        const int n = r0 + tid;
        idx_ws[n]  = i0;
        out_idx[n] = (float)i0;
        out_onehot[(size_t)n * N_E + i0] = 1.0f;
        atomicAdd(&counts[i0], 1);
    }
}

// ---------------------------------------------------------------------------
// K2: z_q_out, z_out, loss partial sums
// ---------------------------------------------------------------------------
__global__ __launch_bounds__(256) void outputs_kernel(
        const float* __restrict__ z, const float* __restrict__ W,
        const int* __restrict__ idx,
        float* __restrict__ zq_out, float* __restrict__ z_out,
        double* __restrict__ loss_acc) {
    const int t  = blockIdx.x * 256 + threadIdx.x;     // 0..ZELEMS-1
    const float zv = z[t];
    const int sp = t & (SPAT - 1);
    const int c  = (t >> 13) & 255;
    const int b  = t >> 21;
    const int n  = (b << 13) + sp;
    const int id = idx[n];
    const float e    = W[id * EDIM + c];
    const float diff = e - zv;        // z_q - zp
    zq_out[t] = zv + diff;            // straight-through value, exact rounding
    z_out[t]  = zv;

    double ds = (double)(diff * diff);
    #pragma unroll
    for (int off = 32; off > 0; off >>= 1) ds += __shfl_down(ds, off);
    __shared__ double bsum[4];
    const int lane = threadIdx.x & 63, w = threadIdx.x >> 6;
    if (lane == 0) bsum[w] = ds;
    __syncthreads();
    if (threadIdx.x == 0)
        atomicAdd(loss_acc, bsum[0] + bsum[1] + bsum[2] + bsum[3]);
}

// ---------------------------------------------------------------------------
// K3: EMA buffer update
// ---------------------------------------------------------------------------
__global__ __launch_bounds__(256) void ema_kernel(const float* __restrict__ W,
                                                  const float* __restrict__ ema,
                                                  float* __restrict__ out) {
    const int t = blockIdx.x * 256 + threadIdx.x;   // 0..1048575
    out[t] = 0.25f * ema[t] + 0.75f * W[t];
}

// ---------------------------------------------------------------------------
// K4: perplexity + loss finalize (single block)
// ---------------------------------------------------------------------------
__global__ __launch_bounds__(256) void final_kernel(
        const int* __restrict__ counts, const double* __restrict__ loss_acc,
        float* __restrict__ out_loss, float* __restrict__ out_perp) {
    __shared__ float ps[256];
    float s = 0.f;
    for (int c = threadIdx.x; c < N_E; c += 256) {
        const float p = (float)counts[c] * (1.0f / (float)NROWS);
        s += p * logf(p + 1e-10f);
    }
    ps[threadIdx.x] = s;
    __syncthreads();
    for (int off = 128; off > 0; off >>= 1) {
        if (threadIdx.x < off) ps[threadIdx.x] += ps[threadIdx.x + off];
        __syncthreads();
    }
    if (threadIdx.x == 0) {
        *out_perp = expf(-ps[0]);
        const float m = (float)(*loss_acc / (double)ZELEMS);
        *out_loss = m + 0.25f * m;
    }
}

// ---------------------------------------------------------------------------
extern "C" void kernel_launch(void* const* d_in, const int* in_sizes, int n_in,
                              void* d_out, int out_size, void* d_ws, size_t ws_size,
                              hipStream_t stream) {
    const float* z   = (const float*)d_in[0];
    const float* W   = (const float*)d_in[1];
    const float* ema = (const float*)d_in[2];
    float* out = (float*)d_out;

    float* out_loss   = out + OFF_LOSS;
    float* out_zq     = out + OFF_ZQ;
    float* out_perp   = out + OFF_PERP;
    float* out_onehot = out + OFF_ONEHOT;
    float* out_idx    = out + OFF_IDX;
    float* out_z      = out + OFF_ZOUT;
    float* out_ema    = out + OFF_EMA;

    // workspace layout
    char* ws = (char*)d_ws;
    double* loss_acc = (double*)ws;                       // 8 B (pad to 16)
    int*    counts   = (int*)(ws + 16);                   // 4096*4 = 16384 B
    int*    idxb     = (int*)(ws + 16 + 16384);           // 16384*4 = 65536 B
    float*  se       = (float*)(ws + 16 + 16384 + 65536); // 4096*4 = 16384 B

    hipMemsetAsync(d_ws, 0, 16 + 16384, stream);                      // loss + counts
    hipMemsetAsync(out_onehot, 0, (size_t)67108864 * 4, stream);      // one-hot zeros

    se_kernel<<<1024, 256, 0, stream>>>(W, se);
    argmin_kernel<<<NROWS / 64, 512, 0, stream>>>(z, W, se, idxb, counts,
                                                  out_idx, out_onehot);
    outputs_kernel<<<ZELEMS / 256, 256, 0, stream>>>(z, W, idxb, out_zq, out_z,
                                                     loss_acc);
    ema_kernel<<<(N_E * EDIM) / 256, 256, 0, stream>>>(W, ema, out_ema);
    final_kernel<<<1, 256, 0, stream>>>(counts, loss_acc, out_loss, out_perp);
}